// Round 1
// baseline (848.616 us; speedup 1.0000x reference)
//
#include <hip/hip_runtime.h>

#define N_LSTM 16
#define ISZ 128
#define HSZ 128
#define BSZ 32
#define TSZ 512
#define G4H 512
#define XROW (N_LSTM * ISZ)   // 2048
#define OROW (N_LSTM * HSZ)   // 2048

typedef __attribute__((ext_vector_type(8))) short s16x8;
typedef __attribute__((ext_vector_type(4))) float f32x4;

static __device__ __forceinline__ unsigned short f2bf(float f) {
    unsigned int u = __builtin_bit_cast(unsigned int, f);
    u += 0x7fffu + ((u >> 16) & 1u);
    return (unsigned short)(u >> 16);
}

static __device__ __forceinline__ float fast_sigmoid(float x) {
    float e = __expf(-x);
    return __builtin_amdgcn_rcpf(1.0f + e);
}

static __device__ __forceinline__ float fast_tanh(float x) {
    x = fminf(fmaxf(x, -20.0f), 20.0f);
    float e = __expf(-2.0f * x);
    return (1.0f - e) * __builtin_amdgcn_rcpf(1.0f + e);
}

// One workgroup = (n, batch-half of 16). 8 waves; wave w owns hidden units
// [16w, 16w+16) x all 4 gates (4 C-tiles = i,f,g,o for its hid chunk).
// W_ih / W_hh held in registers as MFMA B-fragments (64 VGPR each).
// h round-trips through LDS (bf16, double-buffered) each step.
__global__ __launch_bounds__(512, 2) void widelstm_fused(
    const float* __restrict__ x, const float* __restrict__ Wih,
    const float* __restrict__ Whh, const float* __restrict__ bih,
    const float* __restrict__ bhh, float* __restrict__ out)
{
    // +8 pad (16B) keeps ds_read_b128 of A-fragments ~conflict-free
    __shared__ __align__(16) unsigned short xbuf[2][16][136];
    __shared__ __align__(16) unsigned short hbuf[2][16][136];

    const int tid = threadIdx.x;
    const int wv  = tid >> 6;        // wave 0..7 -> hid chunk
    const int ln  = tid & 63;
    const int lm  = ln & 15;         // A-row (m) / C-col
    const int lq  = ln >> 4;         // quad
    const int n    = blockIdx.x >> 1;
    const int half = blockIdx.x & 1;
    const int b0   = half * 16;

    // ---- Load weight B-fragments (once). B[k][col]: lane holds col=lm, k=lq*8+j.
    s16x8 wih[4][4], whh[4][4];
    float bias[4];
    #pragma unroll
    for (int g = 0; g < 4; ++g) {
        const int col = g * 128 + wv * 16 + lm;   // gate-output index in 4H
        bias[g] = bih[n * G4H + col] + bhh[n * G4H + col];
        #pragma unroll
        for (int kt = 0; kt < 4; ++kt) {
            const float* pi = Wih + ((size_t)n * G4H + col) * ISZ + kt * 32 + lq * 8;
            const float* ph = Whh + ((size_t)n * G4H + col) * HSZ + kt * 32 + lq * 8;
            s16x8 a, b;
            #pragma unroll
            for (int j = 0; j < 8; ++j) {
                a[j] = (short)f2bf(pi[j]);
                b[j] = (short)f2bf(ph[j]);
            }
            wih[g][kt] = a;
            whh[g][kt] = b;
        }
    }

    // zero h buffers (h0 = 0)
    for (int i = tid; i < 2 * 16 * 136; i += 512)
        ((unsigned short*)hbuf)[i] = 0;

    // ---- x staging: thread loads 4 consecutive floats of one row per step
    const int sr = tid >> 5;         // 0..15 : batch row within half
    const int sc = (tid & 31) * 4;   // 0..124 : col
    const float* xrow = x + (size_t)(b0 + sr) * TSZ * XROW + n * ISZ + sc;

    float4 xr = *(const float4*)(xrow);   // prefetch t = 0

    float cprev[4] = {0.f, 0.f, 0.f, 0.f};
    float hlast[4] = {0.f, 0.f, 0.f, 0.f};

    const int ocol = n * HSZ + wv * 16 + lm;

    #pragma unroll 1
    for (int t = 0; t < TSZ; ++t) {
        const int buf = t & 1;
        // stage x(t) -> LDS bf16
        unsigned int lo = (unsigned int)f2bf(xr.x) | ((unsigned int)f2bf(xr.y) << 16);
        unsigned int hi = (unsigned int)f2bf(xr.z) | ((unsigned int)f2bf(xr.w) << 16);
        *(uint2*)&xbuf[buf][sr][sc] = make_uint2(lo, hi);
        __syncthreads();
        if (t + 1 < TSZ)
            xr = *(const float4*)(xrow + (size_t)(t + 1) * XROW);

        // A fragments: A[m=lm][k=lq*8+j]
        s16x8 ax[4], ah[4];
        #pragma unroll
        for (int kt = 0; kt < 4; ++kt) {
            ax[kt] = *(const s16x8*)&xbuf[buf][lm][kt * 32 + lq * 8];
            ah[kt] = *(const s16x8*)&hbuf[buf][lm][kt * 32 + lq * 8];
        }

        f32x4 acc[4];
        #pragma unroll
        for (int g = 0; g < 4; ++g)
            acc[g] = (f32x4){bias[g], bias[g], bias[g], bias[g]};
        #pragma unroll
        for (int kt = 0; kt < 4; ++kt) {
            #pragma unroll
            for (int g = 0; g < 4; ++g) {
                acc[g] = __builtin_amdgcn_mfma_f32_16x16x32_bf16(ax[kt], wih[g][kt], acc[g], 0, 0, 0);
                acc[g] = __builtin_amdgcn_mfma_f32_16x16x32_bf16(ah[kt], whh[g][kt], acc[g], 0, 0, 0);
            }
        }

        // epilogue: lane owns (batch row = lq*4+r, hid = 16*wv+lm)
        float* orow = out + (size_t)t * OROW + ocol;
        #pragma unroll
        for (int r = 0; r < 4; ++r) {
            float iv = fast_sigmoid(acc[0][r]);
            float fv = fast_sigmoid(acc[1][r]);
            float gv = fast_tanh(acc[2][r]);
            float ov = fast_sigmoid(acc[3][r]);
            float c  = fv * cprev[r] + iv * gv;
            cprev[r] = c;
            float hv = ov * fast_tanh(c);
            hlast[r] = hv;
            const int row = lq * 4 + r;
            orow[(size_t)(b0 + row) * TSZ * OROW] = hv;
            hbuf[buf ^ 1][row][wv * 16 + lm] = f2bf(hv);
        }
    }

    // finals: h_n, c_n  [1, B, N*H] each
    const size_t hn_off = (size_t)BSZ * TSZ * OROW;
    const size_t cn_off = hn_off + (size_t)BSZ * OROW;
    #pragma unroll
    for (int r = 0; r < 4; ++r) {
        const int row = lq * 4 + r;
        const size_t idx = (size_t)(b0 + row) * OROW + ocol;
        out[hn_off + idx] = hlast[r];
        out[cn_off + idx] = cprev[r];
    }
}

extern "C" void kernel_launch(void* const* d_in, const int* in_sizes, int n_in,
                              void* d_out, int out_size, void* d_ws, size_t ws_size,
                              hipStream_t stream) {
    const float* x   = (const float*)d_in[0];
    const float* Wih = (const float*)d_in[1];
    const float* Whh = (const float*)d_in[2];
    const float* bih = (const float*)d_in[3];
    const float* bhh = (const float*)d_in[4];
    float* out = (float*)d_out;
    widelstm_fused<<<dim3(32), dim3(512), 0, stream>>>(x, Wih, Whh, bih, bhh, out);
}